// Round 9
// baseline (173.441 us; speedup 1.0000x reference)
//
#include <hip/hip_runtime.h>
#include <hip/hip_bf16.h>
#include <math.h>

typedef __bf16 bf16_t;
typedef __attribute__((ext_vector_type(8))) __bf16 bf16x8;
typedef __attribute__((ext_vector_type(4))) __bf16 bf16x4;
typedef __attribute__((ext_vector_type(4))) float f32x4;

#define B_DIM 2
#define S_DIM 2048
#define H_DIM 16
#define DK 64
#define DM 1024
#define KDIM 1024

#define MFMA(a, b, c) __builtin_amdgcn_mfma_f32_16x16x32_bf16((a), (b), (c), 0, 0, 0)

__device__ __forceinline__ void gload_lds16(const bf16_t* g, bf16_t* l) {
    __builtin_amdgcn_global_load_lds(
        (const __attribute__((address_space(1))) void*)g,
        (__attribute__((address_space(3))) void*)l, 16, 0, 0);
}

// ---------------- fp32 -> bf16 convert ----------------
__global__ void cvt_kernel(const float* __restrict__ src, bf16_t* __restrict__ dst, int n) {
    int i = (blockIdx.x * blockDim.x + threadIdx.x) * 4;
    if (i >= n) return;
    float4 v = *reinterpret_cast<const float4*>(src + i);
    bf16x4 o;
    o[0] = (__bf16)v.x; o[1] = (__bf16)v.y; o[2] = (__bf16)v.z; o[3] = (__bf16)v.w;
    *reinterpret_cast<bf16x4*>(dst + i) = o;
}

__global__ void cvt4_kernel(const float* __restrict__ s0, const float* __restrict__ s1,
                            const float* __restrict__ s2, const float* __restrict__ s3,
                            bf16_t* __restrict__ d0, bf16_t* __restrict__ d1,
                            bf16_t* __restrict__ d2, bf16_t* __restrict__ d3, int n) {
    const float* s; bf16_t* d;
    switch (blockIdx.y) {
        case 0: s = s0; d = d0; break;
        case 1: s = s1; d = d1; break;
        case 2: s = s2; d = d2; break;
        default: s = s3; d = d3; break;
    }
    int i = (blockIdx.x * blockDim.x + threadIdx.x) * 4;
    if (i >= n) return;
    float4 v = *reinterpret_cast<const float4*>(s + i);
    bf16x4 o;
    o[0] = (__bf16)v.x; o[1] = (__bf16)v.y; o[2] = (__bf16)v.z; o[3] = (__bf16)v.w;
    *reinterpret_cast<bf16x4*>(d + i) = o;
}

// ---------------- GEMM: Y[m,n] = sum_k A[m,k] * B[n,k]  (B^T layout) ----------------
// Catalog 2-phase pipeline (T3-minimum, race-free with 2 buffers):
//   prologue: STAGE(0); vmcnt(0); barrier
//   per iter: STAGE(t+1, buf^1) -> compute buf -> vmcnt(0); barrier
// MODE 0: QKV projections; RoPE fused into epilogue for z<2 (pair partner is the
//         adjacent lane: col parity == lane parity -> __shfl_xor(v,1)).
// MODE 1: output projection (fp32 out).
template <int MODE>
__global__ __launch_bounds__(256)
void gemm_bt(const bf16_t* __restrict__ A,
             const bf16_t* __restrict__ B0,
             const bf16_t* __restrict__ B1,
             const bf16_t* __restrict__ B2,
             bf16_t* __restrict__ outQ,
             bf16_t* __restrict__ outK,
             bf16_t* __restrict__ outVt,
             float* __restrict__ outF,
             const int* __restrict__ pos) {
    __shared__ bf16_t As[2][128 * 32];
    __shared__ bf16_t Bs[2][128 * 32];

    const int t = threadIdx.x;
    const int z = blockIdx.z;
    const bf16_t* Bm = (MODE == 0) ? (z == 0 ? B0 : (z == 1 ? B1 : B2)) : B0;

    const int m0 = blockIdx.x * 128;
    const int n0 = blockIdx.y * 128;
    const int lane = t & 63;
    const int w = t >> 6;
    const int wr = w >> 1;
    const int wc = w & 1;

    f32x4 acc[4][4] = {};

    const int ar = t >> 2;
    const int ac = (t & 3) * 8;
    const bf16_t* Ag = A + (size_t)m0 * KDIM;
    const bf16_t* Bg = Bm + (size_t)n0 * KDIM;

    const int rr = lane & 15;
    const int ko = (lane >> 4) * 8;

    constexpr int NT = KDIM / 32;

    // prologue: stage tile 0 into buf 0, drain, barrier
    gload_lds16(Ag + (size_t)ar * KDIM + ac,        &As[0][t * 8]);
    gload_lds16(Ag + (size_t)(ar + 64) * KDIM + ac, &As[0][2048 + t * 8]);
    gload_lds16(Bg + (size_t)ar * KDIM + ac,        &Bs[0][t * 8]);
    gload_lds16(Bg + (size_t)(ar + 64) * KDIM + ac, &Bs[0][2048 + t * 8]);
    asm volatile("s_waitcnt vmcnt(0)" ::: "memory");
    __builtin_amdgcn_s_barrier();
    __builtin_amdgcn_sched_barrier(0);

    for (int it = 0; it < NT; ++it) {
        const int cur = it & 1;
        // issue next-tile stage (lands during/after compute; drained at iter end)
        if (it + 1 < NT) {
            const int k1 = (it + 1) * 32;
            gload_lds16(Ag + (size_t)ar * KDIM + k1 + ac,        &As[cur ^ 1][t * 8]);
            gload_lds16(Ag + (size_t)(ar + 64) * KDIM + k1 + ac, &As[cur ^ 1][2048 + t * 8]);
            gload_lds16(Bg + (size_t)ar * KDIM + k1 + ac,        &Bs[cur ^ 1][t * 8]);
            gload_lds16(Bg + (size_t)(ar + 64) * KDIM + k1 + ac, &Bs[cur ^ 1][2048 + t * 8]);
        }

        bf16x8 af[4], bfr[4];
#pragma unroll
        for (int m = 0; m < 4; ++m)
            af[m] = *reinterpret_cast<const bf16x8*>(&As[cur][(wr * 64 + m * 16 + rr) * 32 + ko]);
#pragma unroll
        for (int n = 0; n < 4; ++n)
            bfr[n] = *reinterpret_cast<const bf16x8*>(&Bs[cur][(wc * 64 + n * 16 + rr) * 32 + ko]);
        __builtin_amdgcn_s_setprio(1);
#pragma unroll
        for (int m = 0; m < 4; ++m)
#pragma unroll
            for (int n = 0; n < 4; ++n)
                acc[m][n] = MFMA(af[m], bfr[n], acc[m][n]);
        __builtin_amdgcn_s_setprio(0);

        // drain staged loads, then barrier: next iter may safely overwrite buf cur
        asm volatile("s_waitcnt vmcnt(0)" ::: "memory");
        __builtin_amdgcn_s_barrier();
        __builtin_amdgcn_sched_barrier(0);
    }

    const int rbase = m0 + wr * 64 + (lane >> 4) * 4;
    const int cbase = n0 + wc * 64 + (lane & 15);
#pragma unroll
    for (int m = 0; m < 4; ++m) {
#pragma unroll
        for (int n = 0; n < 4; ++n) {
            const int gn = cbase + n * 16;
            if (MODE == 0) {
                const int h = gn >> 6, d = gn & 63;
                if (z < 2) {
                    // fused RoPE: pair partner in adjacent lane (col parity = lane parity)
                    bf16_t* dst = (z == 0) ? outQ : outK;
                    const float freq = exp2f((float)(d >> 1) * -0.4152410118609203f);
                    const float sgn = (d & 1) ? 1.0f : -1.0f;
#pragma unroll
                    for (int j = 0; j < 4; ++j) {
                        const int gm = rbase + m * 16 + j;
                        const int b = gm >> 11, s = gm & (S_DIM - 1);
                        const float v = acc[m][n][j];
                        const float pv = __shfl_xor(v, 1);
                        const float ang = (float)pos[s] * freq;
                        const float outv = v * cosf(ang) + sgn * pv * sinf(ang);
                        dst[(((size_t)(b * H_DIM + h) * S_DIM + s) << 6) + d] = (__bf16)outv;
                    }
                } else {
                    bf16x4 v;
#pragma unroll
                    for (int j = 0; j < 4; ++j) v[j] = (__bf16)acc[m][n][j];
                    const int gm = rbase + m * 16;
                    const int b = gm >> 11, s = gm & (S_DIM - 1);
                    *reinterpret_cast<bf16x4*>(
                        &outVt[((size_t)(b * H_DIM + h) * DK + d) * S_DIM + s]) = v;
                }
            } else {
#pragma unroll
                for (int j = 0; j < 4; ++j) {
                    const int gm = rbase + m * 16 + j;
                    outF[(size_t)gm * DM + gn] = acc[m][n][j];
                }
            }
        }
    }
}

// ---------------- causal flash attention v7 (unchanged from R7) ----------------
__global__ __launch_bounds__(256)
void attn_kernel(const bf16_t* __restrict__ Q, const bf16_t* __restrict__ Kg,
                 const bf16_t* __restrict__ Vt, bf16_t* __restrict__ O) {
    constexpr int PSTR = 72;
    __shared__ bf16_t Ks[2][64 * 64];
    __shared__ bf16_t Vs[2][64 * 64];
    __shared__ bf16_t P_lds[4][2][16 * PSTR];

    const int t = threadIdx.x;
    const int lane = t & 63;
    const int w = t >> 6;
    const int bh = blockIdx.x >> 4;   // 32 (b,h)
    const int qi = blockIdx.x & 15;
    const int qbH = 31 - qi, qbL = qi;
    const int q0H = qbH * 64 + w * 16;
    const int q0L = qbL * 64 + w * 16;
    const int b = bh >> 4, h = bh & 15;
    const int rr = lane & 15;
    const int hi = lane >> 4;

    const bf16_t* Kbh = Kg + (size_t)bh * S_DIM * DK;
    const bf16_t* Vbh = Vt + (size_t)bh * DK * S_DIM;   // [d][s]
    bf16_t* PwH = P_lds[w][0];
    bf16_t* PwL = P_lds[w][1];

    const int i0 = t, i1 = t + 256;
    const int r0 = i0 >> 3, c0 = ((i0 & 7) ^ (r0 & 7)) * 8;
    const int r1 = i1 >> 3, c1 = ((i1 & 7) ^ (r1 & 7)) * 8;

    // Q fragments, folded scale = (1/8) * log2(e)  -> scores in log2 units
    const float QSCALE = 0.18033688011112042f;
    const bf16_t* QpH = Q + ((size_t)bh * S_DIM + q0H) * DK;
    const bf16_t* QpL = Q + ((size_t)bh * S_DIM + q0L) * DK;
    bf16x8 qfH[2], qfL[2];
    qfH[0] = *reinterpret_cast<const bf16x8*>(&QpH[rr * DK + hi * 8]);
    qfH[1] = *reinterpret_cast<const bf16x8*>(&QpH[rr * DK + 32 + hi * 8]);
    qfL[0] = *reinterpret_cast<const bf16x8*>(&QpL[rr * DK + hi * 8]);
    qfL[1] = *reinterpret_cast<const bf16x8*>(&QpL[rr * DK + 32 + hi * 8]);
#pragma unroll
    for (int i = 0; i < 8; ++i) {
        qfH[0][i] = (__bf16)((float)qfH[0][i] * QSCALE);
        qfH[1][i] = (__bf16)((float)qfH[1][i] * QSCALE);
        qfL[0][i] = (__bf16)((float)qfL[0][i] * QSCALE);
        qfL[1][i] = (__bf16)((float)qfL[1][i] * QSCALE);
    }

    bf16x8 ones;
#pragma unroll
    for (int i = 0; i < 8; ++i) ones[i] = (__bf16)1.0f;

    f32x4 oH[4] = {}, oL[4] = {};
    f32x4 laH = {}, laL = {};
    float mH = -INFINITY, mL = -INFINITY;

    const int ntH = qbH + 1;

    gload_lds16(Kbh + (size_t)r0 * DK + c0, &Ks[0][i0 * 8]);
    gload_lds16(Kbh + (size_t)r1 * DK + c1, &Ks[0][i1 * 8]);
    gload_lds16(Vbh + (size_t)r0 * S_DIM + c0, &Vs[0][i0 * 8]);
    gload_lds16(Vbh + (size_t)r1 * S_DIM + c1, &Vs[0][i1 * 8]);
    __syncthreads();

    for (int tt = 0; tt < ntH; ++tt) {
        const int cur = tt & 1;
        const int kv0 = tt * 64;
        const bool doL = (tt <= qbL);

        if (tt + 1 < ntH) {
            const int kv1 = kv0 + 64;
            bf16_t* Kn = Ks[cur ^ 1];
            bf16_t* Vn = Vs[cur ^ 1];
            gload_lds16(Kbh + (size_t)(kv1 + r0) * DK + c0, &Kn[i0 * 8]);
            gload_lds16(Kbh + (size_t)(kv1 + r1) * DK + c1, &Kn[i1 * 8]);
            gload_lds16(Vbh + (size_t)r0 * S_DIM + kv1 + c0, &Vn[i0 * 8]);
            gload_lds16(Vbh + (size_t)r1 * S_DIM + kv1 + c1, &Vn[i1 * 8]);
        }
        const bf16_t* Kc = Ks[cur];
        const bf16_t* Vc = Vs[cur];

        f32x4 sH[4] = {}, sL[4] = {};
        __builtin_amdgcn_s_setprio(1);
#pragma unroll
        for (int t16 = 0; t16 < 4; ++t16) {
            const int r = t16 * 16 + rr;
            const int sw = (r & 7) * 8;
            bf16x8 kf0 = *reinterpret_cast<const bf16x8*>(&Kc[r * 64 + ((hi * 8) ^ sw)]);
            bf16x8 kf1 = *reinterpret_cast<const bf16x8*>(&Kc[r * 64 + ((32 + hi * 8) ^ sw)]);
            sH[t16] = MFMA(kf0, qfH[0], sH[t16]);
            sH[t16] = MFMA(kf1, qfH[1], sH[t16]);
            if (doL) {
                sL[t16] = MFMA(kf0, qfL[0], sL[t16]);
                sL[t16] = MFMA(kf1, qfL[1], sL[t16]);
            }
        }
        __builtin_amdgcn_s_setprio(0);

        if (tt == qbH) {
            const int qg = q0H + rr;
#pragma unroll
            for (int t16 = 0; t16 < 4; ++t16)
#pragma unroll
                for (int j = 0; j < 4; ++j)
                    if (kv0 + t16 * 16 + hi * 4 + j > qg) sH[t16][j] = -INFINITY;
        }
        if (tt == qbL) {
            const int qg = q0L + rr;
#pragma unroll
            for (int t16 = 0; t16 < 4; ++t16)
#pragma unroll
                for (int j = 0; j < 4; ++j)
                    if (kv0 + t16 * 16 + hi * 4 + j > qg) sL[t16][j] = -INFINITY;
        }

        // ---- softmax H ----
        {
            f32x4 mv = sH[0];
#pragma unroll
            for (int t16 = 1; t16 < 4; ++t16) {
                mv[0] = fmaxf(mv[0], sH[t16][0]); mv[1] = fmaxf(mv[1], sH[t16][1]);
                mv[2] = fmaxf(mv[2], sH[t16][2]); mv[3] = fmaxf(mv[3], sH[t16][3]);
            }
            const float mloc = fmaxf(fmaxf(mv[0], mv[1]), fmaxf(mv[2], mv[3]));
            if (__any(mloc - mH > 8.0f)) {
                float mf = fmaxf(mloc, __shfl_xor(mloc, 16));
                mf = fmaxf(mf, __shfl_xor(mf, 32));
                const float mnew = fmaxf(mH, mf);
                const float scale = exp2f(mH - mnew);
#pragma unroll
                for (int i = 0; i < 4; ++i) laH[i] *= scale;
#pragma unroll
                for (int db = 0; db < 4; ++db)
#pragma unroll
                    for (int j = 0; j < 4; ++j) oH[db][j] *= scale;
                mH = mnew;
            }
#pragma unroll
            for (int t16 = 0; t16 < 4; ++t16) {
                bf16x4 pb;
#pragma unroll
                for (int j = 0; j < 4; ++j) pb[j] = (__bf16)exp2f(sH[t16][j] - mH);
                *reinterpret_cast<bf16x4*>(&PwH[rr * PSTR + t16 * 16 + hi * 4]) = pb;
            }
        }
        // ---- softmax L ----
        if (doL) {
            f32x4 mv = sL[0];
#pragma unroll
            for (int t16 = 1; t16 < 4; ++t16) {
                mv[0] = fmaxf(mv[0], sL[t16][0]); mv[1] = fmaxf(mv[1], sL[t16][1]);
                mv[2] = fmaxf(mv[2], sL[t16][2]); mv[3] = fmaxf(mv[3], sL[t16][3]);
            }
            const float mloc = fmaxf(fmaxf(mv[0], mv[1]), fmaxf(mv[2], mv[3]));
            if (__any(mloc - mL > 8.0f)) {
                float mf = fmaxf(mloc, __shfl_xor(mloc, 16));
                mf = fmaxf(mf, __shfl_xor(mf, 32));
                const float mnew = fmaxf(mL, mf);
                const float scale = exp2f(mL - mnew);
#pragma unroll
                for (int i = 0; i < 4; ++i) laL[i] *= scale;
#pragma unroll
                for (int db = 0; db < 4; ++db)
#pragma unroll
                    for (int j = 0; j < 4; ++j) oL[db][j] *= scale;
                mL = mnew;
            }
#pragma unroll
            for (int t16 = 0; t16 < 4; ++t16) {
                bf16x4 pb;
#pragma unroll
                for (int j = 0; j < 4; ++j) pb[j] = (__bf16)exp2f(sL[t16][j] - mL);
                *reinterpret_cast<bf16x4*>(&PwL[rr * PSTR + t16 * 16 + hi * 4]) = pb;
            }
        }

        // ---- PV + l via ones-MFMA ----
        bf16x8 pH0 = *reinterpret_cast<const bf16x8*>(&PwH[rr * PSTR + hi * 8]);
        bf16x8 pH1 = *reinterpret_cast<const bf16x8*>(&PwH[rr * PSTR + 32 + hi * 8]);
        bf16x8 pL0, pL1;
        if (doL) {
            pL0 = *reinterpret_cast<const bf16x8*>(&PwL[rr * PSTR + hi * 8]);
            pL1 = *reinterpret_cast<const bf16x8*>(&PwL[rr * PSTR + 32 + hi * 8]);
        }
        __builtin_amdgcn_s_setprio(1);
        laH = MFMA(ones, pH0, laH);
        laH = MFMA(ones, pH1, laH);
        if (doL) {
            laL = MFMA(ones, pL0, laL);
            laL = MFMA(ones, pL1, laL);
        }
#pragma unroll
        for (int db = 0; db < 4; ++db) {
            const int vr = db * 16 + rr;
            const int sw = (vr & 7) * 8;
            bf16x8 vf0 = *reinterpret_cast<const bf16x8*>(&Vc[vr * 64 + ((hi * 8) ^ sw)]);
            bf16x8 vf1 = *reinterpret_cast<const bf16x8*>(&Vc[vr * 64 + ((32 + hi * 8) ^ sw)]);
            oH[db] = MFMA(vf0, pH0, oH[db]);
            oH[db] = MFMA(vf1, pH1, oH[db]);
            if (doL) {
                oL[db] = MFMA(vf0, pL0, oL[db]);
                oL[db] = MFMA(vf1, pL1, oL[db]);
            }
        }
        __builtin_amdgcn_s_setprio(0);

        __syncthreads();
    }

    {
        const float linv = 1.0f / laH[0];
#pragma unroll
        for (int db = 0; db < 4; ++db) {
            bf16x4 ov;
#pragma unroll
            for (int j = 0; j < 4; ++j) ov[j] = (__bf16)(oH[db][j] * linv);
            *reinterpret_cast<bf16x4*>(
                &O[((size_t)(b * S_DIM + q0H + rr)) * DM + h * DK + db * 16 + hi * 4]) = ov;
        }
    }
    {
        const float linv = 1.0f / laL[0];
#pragma unroll
        for (int db = 0; db < 4; ++db) {
            bf16x4 ov;
#pragma unroll
            for (int j = 0; j < 4; ++j) ov[j] = (__bf16)(oL[db][j] * linv);
            *reinterpret_cast<bf16x4*>(
                &O[((size_t)(b * S_DIM + q0L + rr)) * DM + h * DK + db * 16 + hi * 4]) = ov;
        }
    }
}

extern "C" void kernel_launch(void* const* d_in, const int* in_sizes, int n_in,
                              void* d_out, int out_size, void* d_ws, size_t ws_size,
                              hipStream_t stream) {
    const float* x  = (const float*)d_in[0];
    const float* Wq = (const float*)d_in[1];
    const float* Wk = (const float*)d_in[2];
    const float* Wv = (const float*)d_in[3];
    const float* Wo = (const float*)d_in[4];
    const int* pos  = (const int*)d_in[5];
    float* out = (float*)d_out;

    char* ws = (char*)d_ws;
    bf16_t* xb  = (bf16_t*)(ws);
    bf16_t* Wqb = (bf16_t*)(ws + (8u << 20));
    bf16_t* Wkb = (bf16_t*)(ws + (10u << 20));
    bf16_t* Wvb = (bf16_t*)(ws + (12u << 20));
    bf16_t* Wob = (bf16_t*)(ws + (14u << 20));
    bf16_t* Qb  = (bf16_t*)(ws + (16u << 20));
    bf16_t* Kb  = (bf16_t*)(ws + (24u << 20));
    bf16_t* Vtb = (bf16_t*)(ws + (32u << 20));
    bf16_t* Ab  = (bf16_t*)(ws);  // reuse xb region after QKV GEMM

    const int NX = B_DIM * S_DIM * DM;
    const int NW = DM * DM;

    cvt_kernel<<<NX / 1024, 256, 0, stream>>>(x, xb, NX);
    cvt4_kernel<<<dim3(NW / 1024, 4), 256, 0, stream>>>(Wq, Wk, Wv, Wo,
                                                        Wqb, Wkb, Wvb, Wob, NW);

    gemm_bt<0><<<dim3(32, 8, 3), 256, 0, stream>>>(xb, Wqb, Wkb, Wvb,
                                                   Qb, Kb, Vtb, nullptr, pos);

    attn_kernel<<<B_DIM * H_DIM * 16, 256, 0, stream>>>(Qb, Kb, Vtb, Ab);

    gemm_bt<1><<<dim3(32, 8, 1), 256, 0, stream>>>(Ab, Wob, nullptr, nullptr,
                                                   nullptr, nullptr, nullptr, out, pos);
}

// Round 10
// 136.227 us; speedup vs baseline: 1.2732x; 1.2732x over previous
//
#include <hip/hip_runtime.h>
#include <hip/hip_bf16.h>
#include <math.h>

typedef __bf16 bf16_t;
typedef __attribute__((ext_vector_type(8))) __bf16 bf16x8;
typedef __attribute__((ext_vector_type(4))) __bf16 bf16x4;
typedef __attribute__((ext_vector_type(4))) float f32x4;

#define B_DIM 2
#define S_DIM 2048
#define H_DIM 16
#define DK 64
#define DM 1024
#define KDIM 1024

#define MFMA(a, b, c) __builtin_amdgcn_mfma_f32_16x16x32_bf16((a), (b), (c), 0, 0, 0)

__device__ __forceinline__ void gload_lds16(const bf16_t* g, bf16_t* l) {
    __builtin_amdgcn_global_load_lds(
        (const __attribute__((address_space(1))) void*)g,
        (__attribute__((address_space(3))) void*)l, 16, 0, 0);
}

// ---------------- fp32 -> bf16 convert ----------------
__global__ void cvt_kernel(const float* __restrict__ src, bf16_t* __restrict__ dst, int n) {
    int i = (blockIdx.x * blockDim.x + threadIdx.x) * 4;
    if (i >= n) return;
    float4 v = *reinterpret_cast<const float4*>(src + i);
    bf16x4 o;
    o[0] = (__bf16)v.x; o[1] = (__bf16)v.y; o[2] = (__bf16)v.z; o[3] = (__bf16)v.w;
    *reinterpret_cast<bf16x4*>(dst + i) = o;
}

__global__ void cvt4_kernel(const float* __restrict__ s0, const float* __restrict__ s1,
                            const float* __restrict__ s2, const float* __restrict__ s3,
                            bf16_t* __restrict__ d0, bf16_t* __restrict__ d1,
                            bf16_t* __restrict__ d2, bf16_t* __restrict__ d3, int n) {
    const float* s; bf16_t* d;
    switch (blockIdx.y) {
        case 0: s = s0; d = d0; break;
        case 1: s = s1; d = d1; break;
        case 2: s = s2; d = d2; break;
        default: s = s3; d = d3; break;
    }
    int i = (blockIdx.x * blockDim.x + threadIdx.x) * 4;
    if (i >= n) return;
    float4 v = *reinterpret_cast<const float4*>(s + i);
    bf16x4 o;
    o[0] = (__bf16)v.x; o[1] = (__bf16)v.y; o[2] = (__bf16)v.z; o[3] = (__bf16)v.w;
    *reinterpret_cast<bf16x4*>(d + i) = o;
}

// ---------------- GEMM: Y[m,n] = sum_k A[m,k] * B[n,k]  (B^T layout) ----------------
// K-loop: R7-proven single-buffer 2-sync structure.
// MODE 0 epilogue: acc -> LDS tile Cs[128][CP] -> cooperative COALESCED writeout.
//   z<2 (Q/K): row-major Cs; readout applies RoPE in fp32 (sincos computed
//              once per (s, j-pair) and reused across the 2 heads); 1KB-contig stores.
//   z==2 (Vt): Cs transposed [c][r]; readout writes 256B-contiguous runs per (h,d).
// MODE 1: output projection, direct fp32 stores (already coalesced).
template <int MODE>
__global__ __launch_bounds__(256)
void gemm_bt(const bf16_t* __restrict__ A,
             const bf16_t* __restrict__ B0,
             const bf16_t* __restrict__ B1,
             const bf16_t* __restrict__ B2,
             bf16_t* __restrict__ outQ,
             bf16_t* __restrict__ outK,
             bf16_t* __restrict__ outVt,
             float* __restrict__ outF,
             const int* __restrict__ pos) {
    constexpr int CP = 136;  // Cs row stride: even, 16B-aligned rows, bank-spread
    __shared__ bf16_t smem[(MODE == 0) ? (128 * CP) : 8192];
    bf16_t* As = smem;
    bf16_t* Bs = smem + 4096;
    bf16_t* Cs = smem;       // reuses As/Bs space after final K-loop sync

    const int t = threadIdx.x;
    const int z = blockIdx.z;
    const bf16_t* Bm = (MODE == 0) ? (z == 0 ? B0 : (z == 1 ? B1 : B2)) : B0;

    const int m0 = blockIdx.x * 128;
    const int n0 = blockIdx.y * 128;
    const int lane = t & 63;
    const int w = t >> 6;
    const int wr = w >> 1;
    const int wc = w & 1;

    f32x4 acc[4][4] = {};

    const int ar = t >> 2;
    const int ac = (t & 3) * 8;
    const bf16_t* Ag = A + (size_t)m0 * KDIM;
    const bf16_t* Bg = Bm + (size_t)n0 * KDIM;

    const int rr = lane & 15;
    const int ko = (lane >> 4) * 8;

    for (int k0 = 0; k0 < KDIM; k0 += 32) {
        gload_lds16(Ag + (size_t)ar * KDIM + k0 + ac,        &As[t * 8]);
        gload_lds16(Ag + (size_t)(ar + 64) * KDIM + k0 + ac, &As[2048 + t * 8]);
        gload_lds16(Bg + (size_t)ar * KDIM + k0 + ac,        &Bs[t * 8]);
        gload_lds16(Bg + (size_t)(ar + 64) * KDIM + k0 + ac, &Bs[2048 + t * 8]);
        __syncthreads();

        bf16x8 af[4], bfr[4];
#pragma unroll
        for (int m = 0; m < 4; ++m)
            af[m] = *reinterpret_cast<const bf16x8*>(&As[(wr * 64 + m * 16 + rr) * 32 + ko]);
#pragma unroll
        for (int n = 0; n < 4; ++n)
            bfr[n] = *reinterpret_cast<const bf16x8*>(&Bs[(wc * 64 + n * 16 + rr) * 32 + ko]);
#pragma unroll
        for (int m = 0; m < 4; ++m)
#pragma unroll
            for (int n = 0; n < 4; ++n)
                acc[m][n] = MFMA(af[m], bfr[n], acc[m][n]);
        __syncthreads();
    }

    const int rlb = wr * 64 + (lane >> 4) * 4;   // local row base
    const int clb = wc * 64 + (lane & 15);       // local col base

    if (MODE == 0) {
        if (z < 2) {
            // ---- Q/K: Cs row-major [r][c] ----
#pragma unroll
            for (int m = 0; m < 4; ++m)
#pragma unroll
                for (int n = 0; n < 4; ++n)
#pragma unroll
                    for (int j = 0; j < 4; ++j)
                        Cs[(rlb + m * 16 + j) * CP + clb + n * 16] = (__bf16)acc[m][n][j];
            __syncthreads();

            bf16_t* dst = (z == 0) ? outQ : outK;
            const int dch = t & 7;        // 16B chunk within head dim (d0 = dch*8)
            const int srow = t >> 3;      // 0..31
            float fr[4];
#pragma unroll
            for (int i = 0; i < 4; ++i)
                fr[i] = exp2f((float)(dch * 4 + i) * -0.4152410118609203f);
#pragma unroll
            for (int p = 0; p < 4; ++p) {
                const int s_loc = p * 32 + srow;
                const int gm = m0 + s_loc;
                const int bb = gm >> 11, sg = gm & (S_DIM - 1);
                const float pv = (float)pos[sg];
                float csv[4], snv[4];
#pragma unroll
                for (int i = 0; i < 4; ++i) {
                    const float a = pv * fr[i];
                    csv[i] = cosf(a); snv[i] = sinf(a);
                }
#pragma unroll
                for (int hc = 0; hc < 2; ++hc) {
                    const bf16x8 vv = *reinterpret_cast<const bf16x8*>(
                        &Cs[s_loc * CP + hc * 64 + dch * 8]);
                    bf16x8 ov;
#pragma unroll
                    for (int i = 0; i < 4; ++i) {
                        const float v0 = (float)vv[2 * i], v1 = (float)vv[2 * i + 1];
                        ov[2 * i]     = (__bf16)(v0 * csv[i] - v1 * snv[i]);
                        ov[2 * i + 1] = (__bf16)(v0 * snv[i] + v1 * csv[i]);
                    }
                    const int h = (n0 >> 6) + hc;
                    *reinterpret_cast<bf16x8*>(
                        &dst[((size_t)(bb * H_DIM + h) * S_DIM + sg) * 64 + dch * 8]) = ov;
                }
            }
        } else {
            // ---- Vt: Cs transposed [c][r] (bf16x4 over j = consecutive r) ----
#pragma unroll
            for (int m = 0; m < 4; ++m)
#pragma unroll
                for (int n = 0; n < 4; ++n) {
                    const int cl = clb + n * 16;
                    bf16x4 v4;
#pragma unroll
                    for (int j = 0; j < 4; ++j) v4[j] = (__bf16)acc[m][n][j];
                    *reinterpret_cast<bf16x4*>(&Cs[cl * CP + rlb + m * 16]) = v4;
                }
            __syncthreads();

            const int cl = t >> 1, sh = t & 1;
            const int cg = n0 + cl, h = cg >> 6, d = cg & 63;
            const int bb = m0 >> 11, s0g = m0 & (S_DIM - 1);
            bf16_t* vdst = &outVt[((size_t)(bb * H_DIM + h) * DK + d) * S_DIM + s0g + sh * 64];
#pragma unroll
            for (int i = 0; i < 8; ++i)
                *reinterpret_cast<bf16x8*>(&vdst[i * 8]) =
                    *reinterpret_cast<const bf16x8*>(&Cs[cl * CP + sh * 64 + i * 8]);
        }
    } else {
        const int rbase = m0 + rlb;
        const int cbase = n0 + clb;
#pragma unroll
        for (int m = 0; m < 4; ++m)
#pragma unroll
            for (int n = 0; n < 4; ++n)
#pragma unroll
                for (int j = 0; j < 4; ++j)
                    outF[(size_t)(rbase + m * 16 + j) * DM + cbase + n * 16] = acc[m][n][j];
    }
}

// ---------------- causal flash attention v7 (unchanged) ----------------
__global__ __launch_bounds__(256)
void attn_kernel(const bf16_t* __restrict__ Q, const bf16_t* __restrict__ Kg,
                 const bf16_t* __restrict__ Vt, bf16_t* __restrict__ O) {
    constexpr int PSTR = 72;
    __shared__ bf16_t Ks[2][64 * 64];
    __shared__ bf16_t Vs[2][64 * 64];
    __shared__ bf16_t P_lds[4][2][16 * PSTR];

    const int t = threadIdx.x;
    const int lane = t & 63;
    const int w = t >> 6;
    const int bh = blockIdx.x >> 4;
    const int qi = blockIdx.x & 15;
    const int qbH = 31 - qi, qbL = qi;
    const int q0H = qbH * 64 + w * 16;
    const int q0L = qbL * 64 + w * 16;
    const int b = bh >> 4, h = bh & 15;
    const int rr = lane & 15;
    const int hi = lane >> 4;

    const bf16_t* Kbh = Kg + (size_t)bh * S_DIM * DK;
    const bf16_t* Vbh = Vt + (size_t)bh * DK * S_DIM;
    bf16_t* PwH = P_lds[w][0];
    bf16_t* PwL = P_lds[w][1];

    const int i0 = t, i1 = t + 256;
    const int r0 = i0 >> 3, c0 = ((i0 & 7) ^ (r0 & 7)) * 8;
    const int r1 = i1 >> 3, c1 = ((i1 & 7) ^ (r1 & 7)) * 8;

    const float QSCALE = 0.18033688011112042f;
    const bf16_t* QpH = Q + ((size_t)bh * S_DIM + q0H) * DK;
    const bf16_t* QpL = Q + ((size_t)bh * S_DIM + q0L) * DK;
    bf16x8 qfH[2], qfL[2];
    qfH[0] = *reinterpret_cast<const bf16x8*>(&QpH[rr * DK + hi * 8]);
    qfH[1] = *reinterpret_cast<const bf16x8*>(&QpH[rr * DK + 32 + hi * 8]);
    qfL[0] = *reinterpret_cast<const bf16x8*>(&QpL[rr * DK + hi * 8]);
    qfL[1] = *reinterpret_cast<const bf16x8*>(&QpL[rr * DK + 32 + hi * 8]);
#pragma unroll
    for (int i = 0; i < 8; ++i) {
        qfH[0][i] = (__bf16)((float)qfH[0][i] * QSCALE);
        qfH[1][i] = (__bf16)((float)qfH[1][i] * QSCALE);
        qfL[0][i] = (__bf16)((float)qfL[0][i] * QSCALE);
        qfL[1][i] = (__bf16)((float)qfL[1][i] * QSCALE);
    }

    bf16x8 ones;
#pragma unroll
    for (int i = 0; i < 8; ++i) ones[i] = (__bf16)1.0f;

    f32x4 oH[4] = {}, oL[4] = {};
    f32x4 laH = {}, laL = {};
    float mH = -INFINITY, mL = -INFINITY;

    const int ntH = qbH + 1;

    gload_lds16(Kbh + (size_t)r0 * DK + c0, &Ks[0][i0 * 8]);
    gload_lds16(Kbh + (size_t)r1 * DK + c1, &Ks[0][i1 * 8]);
    gload_lds16(Vbh + (size_t)r0 * S_DIM + c0, &Vs[0][i0 * 8]);
    gload_lds16(Vbh + (size_t)r1 * S_DIM + c1, &Vs[0][i1 * 8]);
    __syncthreads();

    for (int tt = 0; tt < ntH; ++tt) {
        const int cur = tt & 1;
        const int kv0 = tt * 64;
        const bool doL = (tt <= qbL);

        if (tt + 1 < ntH) {
            const int kv1 = kv0 + 64;
            bf16_t* Kn = Ks[cur ^ 1];
            bf16_t* Vn = Vs[cur ^ 1];
            gload_lds16(Kbh + (size_t)(kv1 + r0) * DK + c0, &Kn[i0 * 8]);
            gload_lds16(Kbh + (size_t)(kv1 + r1) * DK + c1, &Kn[i1 * 8]);
            gload_lds16(Vbh + (size_t)r0 * S_DIM + kv1 + c0, &Vn[i0 * 8]);
            gload_lds16(Vbh + (size_t)r1 * S_DIM + kv1 + c1, &Vn[i1 * 8]);
        }
        const bf16_t* Kc = Ks[cur];
        const bf16_t* Vc = Vs[cur];

        f32x4 sH[4] = {}, sL[4] = {};
        __builtin_amdgcn_s_setprio(1);
#pragma unroll
        for (int t16 = 0; t16 < 4; ++t16) {
            const int r = t16 * 16 + rr;
            const int sw = (r & 7) * 8;
            bf16x8 kf0 = *reinterpret_cast<const bf16x8*>(&Kc[r * 64 + ((hi * 8) ^ sw)]);
            bf16x8 kf1 = *reinterpret_cast<const bf16x8*>(&Kc[r * 64 + ((32 + hi * 8) ^ sw)]);
            sH[t16] = MFMA(kf0, qfH[0], sH[t16]);
            sH[t16] = MFMA(kf1, qfH[1], sH[t16]);
            if (doL) {
                sL[t16] = MFMA(kf0, qfL[0], sL[t16]);
                sL[t16] = MFMA(kf1, qfL[1], sL[t16]);
            }
        }
        __builtin_amdgcn_s_setprio(0);

        if (tt == qbH) {
            const int qg = q0H + rr;
#pragma unroll
            for (int t16 = 0; t16 < 4; ++t16)
#pragma unroll
                for (int j = 0; j < 4; ++j)
                    if (kv0 + t16 * 16 + hi * 4 + j > qg) sH[t16][j] = -INFINITY;
        }
        if (tt == qbL) {
            const int qg = q0L + rr;
#pragma unroll
            for (int t16 = 0; t16 < 4; ++t16)
#pragma unroll
                for (int j = 0; j < 4; ++j)
                    if (kv0 + t16 * 16 + hi * 4 + j > qg) sL[t16][j] = -INFINITY;
        }

        {
            f32x4 mv = sH[0];
#pragma unroll
            for (int t16 = 1; t16 < 4; ++t16) {
                mv[0] = fmaxf(mv[0], sH[t16][0]); mv[1] = fmaxf(mv[1], sH[t16][1]);
                mv[2] = fmaxf(mv[2], sH[t16][2]); mv[3] = fmaxf(mv[3], sH[t16][3]);
            }
            const float mloc = fmaxf(fmaxf(mv[0], mv[1]), fmaxf(mv[2], mv[3]));
            if (__any(mloc - mH > 8.0f)) {
                float mf = fmaxf(mloc, __shfl_xor(mloc, 16));
                mf = fmaxf(mf, __shfl_xor(mf, 32));
                const float mnew = fmaxf(mH, mf);
                const float scale = exp2f(mH - mnew);
#pragma unroll
                for (int i = 0; i < 4; ++i) laH[i] *= scale;
#pragma unroll
                for (int db = 0; db < 4; ++db)
#pragma unroll
                    for (int j = 0; j < 4; ++j) oH[db][j] *= scale;
                mH = mnew;
            }
#pragma unroll
            for (int t16 = 0; t16 < 4; ++t16) {
                bf16x4 pb;
#pragma unroll
                for (int j = 0; j < 4; ++j) pb[j] = (__bf16)exp2f(sH[t16][j] - mH);
                *reinterpret_cast<bf16x4*>(&PwH[rr * PSTR + t16 * 16 + hi * 4]) = pb;
            }
        }
        if (doL) {
            f32x4 mv = sL[0];
#pragma unroll
            for (int t16 = 1; t16 < 4; ++t16) {
                mv[0] = fmaxf(mv[0], sL[t16][0]); mv[1] = fmaxf(mv[1], sL[t16][1]);
                mv[2] = fmaxf(mv[2], sL[t16][2]); mv[3] = fmaxf(mv[3], sL[t16][3]);
            }
            const float mloc = fmaxf(fmaxf(mv[0], mv[1]), fmaxf(mv[2], mv[3]));
            if (__any(mloc - mL > 8.0f)) {
                float mf = fmaxf(mloc, __shfl_xor(mloc, 16));
                mf = fmaxf(mf, __shfl_xor(mf, 32));
                const float mnew = fmaxf(mL, mf);
                const float scale = exp2f(mL - mnew);
#pragma unroll
                for (int i = 0; i < 4; ++i) laL[i] *= scale;
#pragma unroll
                for (int db = 0; db < 4; ++db)
#pragma unroll
                    for (int j = 0; j < 4; ++j) oL[db][j] *= scale;
                mL = mnew;
            }
#pragma unroll
            for (int t16 = 0; t16 < 4; ++t16) {
                bf16x4 pb;
#pragma unroll
                for (int j = 0; j < 4; ++j) pb[j] = (__bf16)exp2f(sL[t16][j] - mL);
                *reinterpret_cast<bf16x4*>(&PwL[rr * PSTR + t16 * 16 + hi * 4]) = pb;
            }
        }

        bf16x8 pH0 = *reinterpret_cast<const bf16x8*>(&PwH[rr * PSTR + hi * 8]);
        bf16x8 pH1 = *reinterpret_cast<const bf16x8*>(&PwH[rr * PSTR + 32 + hi * 8]);
        bf16x8 pL0, pL1;
        if (doL) {
            pL0 = *reinterpret_cast<const bf16x8*>(&PwL[rr * PSTR + hi * 8]);
            pL1 = *reinterpret_cast<const bf16x8*>(&PwL[rr * PSTR + 32 + hi * 8]);
        }
        __builtin_amdgcn_s_setprio(1);
        laH = MFMA(ones, pH0, laH);
        laH = MFMA(ones, pH1, laH);
        if (doL) {
            laL = MFMA(ones, pL0, laL);
            laL = MFMA(ones, pL1, laL);
        }
#pragma unroll
        for (int db = 0; db < 4; ++db) {
            const int vr = db * 16 + rr;
            const int sw = (vr & 7) * 8;
            bf16x8 vf0 = *reinterpret_cast<const bf16x8*>(&Vc[vr * 64 + ((hi * 8) ^ sw)]);
            bf16x8 vf1 = *reinterpret_cast<const bf16x8*>(&Vc[vr * 64 + ((32 + hi * 8) ^ sw)]);
            oH[db] = MFMA(vf0, pH0, oH[db]);
            oH[db] = MFMA(vf1, pH1, oH[db]);
            if (doL) {
                oL[db] = MFMA(vf0, pL0, oL[db]);
                oL[db] = MFMA(vf1, pL1, oL[db]);
            }
        }
        __builtin_amdgcn_s_setprio(0);

        __syncthreads();
    }

    {
        const float linv = 1.0f / laH[0];
#pragma unroll
        for (int db = 0; db < 4; ++db) {
            bf16x4 ov;
#pragma unroll
            for (int j = 0; j < 4; ++j) ov[j] = (__bf16)(oH[db][j] * linv);
            *reinterpret_cast<bf16x4*>(
                &O[((size_t)(b * S_DIM + q0H + rr)) * DM + h * DK + db * 16 + hi * 4]) = ov;
        }
    }
    {
        const float linv = 1.0f / laL[0];
#pragma unroll
        for (int db = 0; db < 4; ++db) {
            bf16x4 ov;
#pragma unroll
            for (int j = 0; j < 4; ++j) ov[j] = (__bf16)(oL[db][j] * linv);
            *reinterpret_cast<bf16x4*>(
                &O[((size_t)(b * S_DIM + q0L + rr)) * DM + h * DK + db * 16 + hi * 4]) = ov;
        }
    }
}

extern "C" void kernel_launch(void* const* d_in, const int* in_sizes, int n_in,
                              void* d_out, int out_size, void* d_ws, size_t ws_size,
                              hipStream_t stream) {
    const float* x  = (const float*)d_in[0];
    const float* Wq = (const float*)d_in[1];
    const float* Wk = (const float*)d_in[2];
    const float* Wv = (const float*)d_in[3];
    const float* Wo = (const float*)d_in[4];
    const int* pos  = (const int*)d_in[5];
    float* out = (float*)d_out;

    char* ws = (char*)d_ws;
    bf16_t* xb  = (bf16_t*)(ws);
    bf16_t* Wqb = (bf16_t*)(ws + (8u << 20));
    bf16_t* Wkb = (bf16_t*)(ws + (10u << 20));
    bf16_t* Wvb = (bf16_t*)(ws + (12u << 20));
    bf16_t* Wob = (bf16_t*)(ws + (14u << 20));
    bf16_t* Qb  = (bf16_t*)(ws + (16u << 20));
    bf16_t* Kb  = (bf16_t*)(ws + (24u << 20));
    bf16_t* Vtb = (bf16_t*)(ws + (32u << 20));
    bf16_t* Ab  = (bf16_t*)(ws);  // reuse xb region after QKV GEMM

    const int NX = B_DIM * S_DIM * DM;
    const int NW = DM * DM;

    cvt_kernel<<<NX / 1024, 256, 0, stream>>>(x, xb, NX);
    cvt4_kernel<<<dim3(NW / 1024, 4), 256, 0, stream>>>(Wq, Wk, Wv, Wo,
                                                        Wqb, Wkb, Wvb, Wob, NW);

    gemm_bt<0><<<dim3(32, 8, 3), 256, 0, stream>>>(xb, Wqb, Wkb, Wvb,
                                                   Qb, Kb, Vtb, nullptr, pos);

    attn_kernel<<<B_DIM * H_DIM * 16, 256, 0, stream>>>(Qb, Kb, Vtb, Ab);

    gemm_bt<1><<<dim3(32, 8, 1), 256, 0, stream>>>(Ab, Wob, nullptr, nullptr,
                                                   nullptr, nullptr, nullptr, out, pos);
}